// Round 7
// baseline (2654.774 us; speedup 1.0000x reference)
//
#include <hip/hip_runtime.h>

// TemporalCausalMaps on MI355X (gfx950), round 7.
// Anti-diagonal wavefront (round 6) + per-diagonal memory clobber to stop
// LICM from hoisting per-cell weight loads out of the d-loop (round 6's
// 1.35 GB scratch-spill regression). Weights reload per cell from L1/L2.
// Block = 512 threads = 8 waves, wave n = node n; cell (idx,n) depends on
// (idx-1,n) and (idx,n-1), both on the previous diagonal. One __syncthreads
// per diagonal (15 total); intra-cell ordering is in-wave via s_waitcnt.

#define NT 512
#define CELL 1544  // per-cell LDS floats (1536 + 8 pad)

__device__ __forceinline__ void wave_sync() {
  asm volatile("s_waitcnt lgkmcnt(0)" ::: "memory");
}

__device__ __forceinline__ float sigm(float x) { return 1.0f / (1.0f + __expf(-x)); }
__device__ __forceinline__ float tanh_fast(float x) {
  x = fminf(15.0f, fmaxf(-15.0f, x));
  float e = __expf(2.0f * x);
  return (e - 1.0f) / (e + 1.0f);
}
__device__ __forceinline__ float leaky(float x) { return x >= 0.0f ? x : 0.01f * x; }

template <int N4>
__device__ __forceinline__ float dotv(const float* __restrict__ w, const float* h) {
  const float4* w4 = reinterpret_cast<const float4*>(w);
  const float4* h4 = reinterpret_cast<const float4*>(h);
  float acc = 0.0f;
#pragma unroll
  for (int i = 0; i < N4; ++i) {
    float4 a = w4[i], b = h4[i];
    acc = fmaf(a.x, b.x, acc); acc = fmaf(a.y, b.y, acc);
    acc = fmaf(a.z, b.z, acc); acc = fmaf(a.w, b.w, acc);
  }
  return acc;
}

// Per-cell region R (floats):
//  s_x  [8][48] @0      s_h [8][24] @384   s_g [8][24] @576
//  s_gi [8][72] @768    s_y [8][24] @1344
//  overlays (disjoint lifetimes): s_ch[8][64]@768, s_d1(stride 68)@0,
//  s_d2(stride 68)@768
// Block total: 8*1544 + 64 (s_dec) = 12416 floats = 49664 B.
__global__ __launch_bounds__(NT) void tcm_kernel(
    const float* __restrict__ z,
    const float* __restrict__ cond_w1, const float* __restrict__ cond_b1,
    const float* __restrict__ cond_w2, const float* __restrict__ cond_b2,
    const float* __restrict__ proj_w, const float* __restrict__ proj_b,
    const float* __restrict__ gpw, const float* __restrict__ gpb,
    const float* __restrict__ gru_wih, const float* __restrict__ gru_whh,
    const float* __restrict__ gru_bih, const float* __restrict__ gru_bhh,
    const float* __restrict__ cm_w1, const float* __restrict__ cm_b1,
    const float* __restrict__ cm_w2, const float* __restrict__ cm_b2,
    const float* __restrict__ cm_w3, const float* __restrict__ cm_b3,
    const int* __restrict__ endw,
    float* __restrict__ out, int Btot) {
  __shared__ __align__(16) float lds[8 * CELL + 64];
  const int tid  = threadIdx.x;
  const int lane = tid & 63;
  const int n    = tid >> 6;   // wave index = node
  const int b    = blockIdx.x;
  const int T    = endw[0];

  float* R     = lds + n * CELL;
  float* s_x   = R;
  float* s_h   = R + 384;
  float* s_g   = R + 576;
  float* s_gi  = R + 768;
  float* s_y   = R + 1344;
  float* s_ch  = R + 768;      // overlay s_gi (used before it)
  float* s_d1  = R;            // overlay s_x/s_h, stride 68
  float* s_d2  = R + 768;      // overlay s_gi, stride 68
  float* s_dec = lds + 8 * CELL;  // [node][t]

  if (tid < 64) s_dec[tid] = 0.0f;
  __syncthreads();

  const int c_src = lane >> 5;   // 0 = self, 1 = predecessor
  const int c_k   = lane & 31;

#pragma unroll 1
  for (int d = 0; d < T + 7; ++d) {
    // Defeat LICM: without this, every per-cell weight load is d-invariant
    // (n is fixed per wave) and gets hoisted => ~250 VGPRs live => 1.3 GB
    // of scratch spills (round 6). The clobber forces per-cell reloads,
    // which hit L1/L2 (all blocks share the same 460 KB of weights).
    asm volatile("" ::: "memory");
    const int idx = d - n;
    if (idx >= 0 && idx < T) {
      const int L = idx + 1;
      // ---- stage 1a: z prefix copy (float4)
      {
        const float4* z4 = reinterpret_cast<const float4*>(
            z + ((size_t)n * Btot + b) * 256);
        float4* x4 = reinterpret_cast<float4*>(s_x);
#pragma unroll 1
        for (int it = lane; it < L * 8; it += 64) {
          int t = it >> 3, q = it & 7;
          x4[t * 12 + q] = z4[t * 8 + q];
        }
      }
      // ---- cond ph1: relu hidden, lane=(src,k); row idx gated later
      if (idx > 0) {
        int nn = (c_src && n > 0) ? n - 1 : n;
        float w1v = cond_w1[nn * 32 + c_k];
        float b1v = cond_b1[nn * 32 + c_k];
#pragma unroll 1
        for (int t = 0; t < L; ++t) {
          float xv = s_dec[nn * 8 + t];
          s_ch[t * 64 + lane] = fmaxf(fmaf(xv, w1v, b1v), 0.0f);
        }
      }
      wave_sync();
      // ---- cond ph2: lanes 0..15 = output col c
      if (lane < 16) {
        int c = lane;
        bool self = c < 8;
        int nn = self ? n : n - 1;
        int e = self ? c : c - 8;
        bool valid = self ? (idx > 0) : (n > 0 && idx > 0);
        float4 W2[8];
        float bb = 0.0f;
        if (valid) {
          const float4* w4 = reinterpret_cast<const float4*>(
              cond_w2 + (size_t)(nn * 8 + e) * 32);
#pragma unroll
          for (int i = 0; i < 8; ++i) W2[i] = w4[i];
          bb = cond_b2[nn * 8 + e];
        }
#pragma unroll 1
        for (int t = 0; t < L; ++t) {
          float v = 0.0f;
          if (valid && (!self || t < idx)) {
            const float4* c4 = reinterpret_cast<const float4*>(
                s_ch + t * 64 + (self ? 0 : 32));
            float acc = bb;
#pragma unroll
            for (int i = 0; i < 8; ++i) {
              float4 a = W2[i], hh = c4[i];
              acc = fmaf(a.x, hh.x, acc); acc = fmaf(a.y, hh.y, acc);
              acc = fmaf(a.z, hh.z, acc); acc = fmaf(a.w, hh.w, acc);
            }
            v = acc;
          }
          s_x[t * 48 + 32 + c] = v;
        }
      }
      wave_sync();
      // ---- proj -> leaky: lanes 0..23 = row j
      if (lane < 24) {
        float4 W[12];
        const float4* w4 = reinterpret_cast<const float4*>(
            proj_w + (size_t)(n * 24 + lane) * 48);
#pragma unroll
        for (int i = 0; i < 12; ++i) W[i] = w4[i];
        float bb = proj_b[n * 24 + lane];
#pragma unroll 1
        for (int t = 0; t < L; ++t) {
          const float4* x4 = reinterpret_cast<const float4*>(s_x + t * 48);
          float acc = bb;
#pragma unroll
          for (int i = 0; i < 12; ++i) {
            float4 a = W[i], hh = x4[i];
            acc = fmaf(a.x, hh.x, acc); acc = fmaf(a.y, hh.y, acc);
            acc = fmaf(a.z, hh.z, acc); acc = fmaf(a.w, hh.w, acc);
          }
          s_h[t * 24 + lane] = leaky(acc);
        }
      }
      wave_sync();
      // ---- gru_proj: lanes 0..23 = row j
      if (lane < 24) {
        float4 W[6];
        const float4* w4 = reinterpret_cast<const float4*>(gpw + lane * 24);
#pragma unroll
        for (int i = 0; i < 6; ++i) W[i] = w4[i];
        float bb = gpb[lane];
#pragma unroll 1
        for (int t = 0; t < L; ++t) {
          const float4* h4 = reinterpret_cast<const float4*>(s_h + t * 24);
          float acc = bb;
#pragma unroll
          for (int i = 0; i < 6; ++i) {
            float4 a = W[i], hh = h4[i];
            acc = fmaf(a.x, hh.x, acc); acc = fmaf(a.y, hh.y, acc);
            acc = fmaf(a.z, hh.z, acc); acc = fmaf(a.w, hh.w, acc);
          }
          s_g[t * 24 + lane] = acc;
        }
      }
      wave_sync();
      // ---- GRU, 2 layers, all wave-local
      const float* srcp = s_g;
#pragma unroll 1
      for (int l = 0; l < 2; ++l) {
        const int nl = n * 2 + l;
        const float* wih = gru_wih + (size_t)nl * 72 * 24;
        const float* bih = gru_bih + nl * 72;
        // input gates: lane=row 0..63 (+ rows 64..71 on lanes 0..7)
        {
          float4 WA[6], WB[6];
          const float4* wa = reinterpret_cast<const float4*>(
              wih + (size_t)lane * 24);
          const float4* wb = reinterpret_cast<const float4*>(
              wih + (size_t)(64 + (lane & 7)) * 24);
#pragma unroll
          for (int i = 0; i < 6; ++i) { WA[i] = wa[i]; WB[i] = wb[i]; }
          float bA = bih[lane];
          float bB = bih[64 + (lane & 7)];
#pragma unroll 1
          for (int t = 0; t < L; ++t) {
            const float4* h4 = reinterpret_cast<const float4*>(srcp + t * 24);
            float accA = bA, accB = bB;
#pragma unroll
            for (int i = 0; i < 6; ++i) {
              float4 hh = h4[i];
              accA = fmaf(WA[i].x, hh.x, accA); accA = fmaf(WA[i].y, hh.y, accA);
              accA = fmaf(WA[i].z, hh.z, accA); accA = fmaf(WA[i].w, hh.w, accA);
              accB = fmaf(WB[i].x, hh.x, accB); accB = fmaf(WB[i].y, hh.y, accB);
              accB = fmaf(WB[i].z, hh.z, accB); accB = fmaf(WB[i].w, hh.w, accB);
            }
            s_gi[t * 72 + lane] = accA;
            if (lane < 8) s_gi[t * 72 + 64 + lane] = accB;
          }
        }
        wave_sync();
        // recurrence: h broadcast via __shfl, no barriers
        {
          const float* whh = gru_whh + (size_t)nl * 72 * 24;
          const float* bhh = gru_bhh + nl * 72;
          int jm = lane < 24 ? lane : (lane < 48 ? lane - 24 : lane - 48);
          float4 Wr[6], Wz[6], Wn[6];
          {
            const float4* wr4 = reinterpret_cast<const float4*>(whh + jm * 24);
            const float4* wz4 = reinterpret_cast<const float4*>(whh + (24 + jm) * 24);
            const float4* wn4 = reinterpret_cast<const float4*>(whh + (48 + jm) * 24);
#pragma unroll
            for (int i = 0; i < 6; ++i) { Wr[i] = wr4[i]; Wz[i] = wz4[i]; Wn[i] = wn4[i]; }
          }
          float bR = bhh[jm], bZ = bhh[24 + jm], bN = bhh[48 + jm];
          float h = 0.0f;
#pragma unroll 1
          for (int t = 0; t < L; ++t) {
            float gr = bR, gz = bZ, gn = bN;
#pragma unroll
            for (int q = 0; q < 6; ++q) {
              float h0 = __shfl(h, q * 4 + 0);
              float h1 = __shfl(h, q * 4 + 1);
              float h2 = __shfl(h, q * 4 + 2);
              float h3 = __shfl(h, q * 4 + 3);
              gr = fmaf(Wr[q].x, h0, gr); gr = fmaf(Wr[q].y, h1, gr);
              gr = fmaf(Wr[q].z, h2, gr); gr = fmaf(Wr[q].w, h3, gr);
              gz = fmaf(Wz[q].x, h0, gz); gz = fmaf(Wz[q].y, h1, gz);
              gz = fmaf(Wz[q].z, h2, gz); gz = fmaf(Wz[q].w, h3, gz);
              gn = fmaf(Wn[q].x, h0, gn); gn = fmaf(Wn[q].y, h1, gn);
              gn = fmaf(Wn[q].w, h3, gn); gn = fmaf(Wn[q].z, h2, gn);
            }
            const float* gi = s_gi + t * 72;
            float r   = sigm(gi[jm] + gr);
            float zg  = sigm(gi[24 + jm] + gz);
            float nn2 = tanh_fast(gi[48 + jm] + r * gn);
            h = fmaf(zg, h - nn2, nn2);  // (1-z)*n + z*h
            if (lane < 24) s_y[t * 24 + lane] = h;
          }
        }
        wave_sync();
        srcp = s_y;
      }
      // ---- causal map layer 1: lane = j
      {
        float4 W[6];
        const float4* w4 = reinterpret_cast<const float4*>(
            cm_w1 + (size_t)(n * 64 + lane) * 24);
#pragma unroll
        for (int i = 0; i < 6; ++i) W[i] = w4[i];
        float bb = cm_b1[n * 64 + lane];
#pragma unroll 1
        for (int t = 0; t < L; ++t) {
          const float4* y4 = reinterpret_cast<const float4*>(s_y + t * 24);
          float acc = bb;
#pragma unroll
          for (int i = 0; i < 6; ++i) {
            float4 a = W[i], hh = y4[i];
            acc = fmaf(a.x, hh.x, acc); acc = fmaf(a.y, hh.y, acc);
            acc = fmaf(a.z, hh.z, acc); acc = fmaf(a.w, hh.w, acc);
          }
          s_d1[t * 68 + lane] = fmaxf(acc, 0.0f);
        }
      }
      wave_sync();
      // ---- causal map layer 2: lane = j
      {
        float4 W[16];
        const float4* w4 = reinterpret_cast<const float4*>(
            cm_w2 + (size_t)(n * 64 + lane) * 64);
#pragma unroll
        for (int i = 0; i < 16; ++i) W[i] = w4[i];
        float bb = cm_b2[n * 64 + lane];
#pragma unroll 1
        for (int t = 0; t < L; ++t) {
          const float4* d4 = reinterpret_cast<const float4*>(s_d1 + t * 68);
          float acc = bb;
#pragma unroll
          for (int i = 0; i < 16; ++i) {
            float4 a = W[i], hh = d4[i];
            acc = fmaf(a.x, hh.x, acc); acc = fmaf(a.y, hh.y, acc);
            acc = fmaf(a.z, hh.z, acc); acc = fmaf(a.w, hh.w, acc);
          }
          s_d2[t * 68 + lane] = fmaxf(acc, 0.0f);
        }
      }
      wave_sync();
      // ---- causal map layer 3 -> s_dec + emit (lane = t)
      if (lane < L) {
        int t = lane;
        float dv = cm_b3[n] + dotv<16>(cm_w3 + n * 64, s_d2 + t * 68);
        s_dec[n * 8 + t] = dv;
        if (t == idx)
          out[((size_t)b * T + idx) * 8 + n] = dv;
      }
    }
    __syncthreads();  // publish s_dec to the next diagonal
  }
}

extern "C" void kernel_launch(void* const* d_in, const int* in_sizes, int n_in,
                              void* d_out, int out_size, void* d_ws, size_t ws_size,
                              hipStream_t stream) {
  const float* z       = (const float*)d_in[0];
  const float* cond_w1 = (const float*)d_in[1];
  const float* cond_b1 = (const float*)d_in[2];
  const float* cond_w2 = (const float*)d_in[3];
  const float* cond_b2 = (const float*)d_in[4];
  const float* proj_w  = (const float*)d_in[5];
  const float* proj_b  = (const float*)d_in[6];
  const float* gpw     = (const float*)d_in[7];
  const float* gpb     = (const float*)d_in[8];
  const float* gru_wih = (const float*)d_in[9];
  const float* gru_whh = (const float*)d_in[10];
  const float* gru_bih = (const float*)d_in[11];
  const float* gru_bhh = (const float*)d_in[12];
  const float* cm_w1   = (const float*)d_in[13];
  const float* cm_b1   = (const float*)d_in[14];
  const float* cm_w2   = (const float*)d_in[15];
  const float* cm_b2   = (const float*)d_in[16];
  const float* cm_w3   = (const float*)d_in[17];
  const float* cm_b3   = (const float*)d_in[18];
  const int*   endw    = (const int*)d_in[19];
  float* out = (float*)d_out;

  int Btot = in_sizes[0] / (8 * 8 * 32);  // z: [8, B, 8, 32]

  tcm_kernel<<<Btot, NT, 0, stream>>>(
      z, cond_w1, cond_b1, cond_w2, cond_b2, proj_w, proj_b, gpw, gpb,
      gru_wih, gru_whh, gru_bih, gru_bhh, cm_w1, cm_b1, cm_w2, cm_b2,
      cm_w3, cm_b3, endw, out, Btot);
}

// Round 8
// 1342.961 us; speedup vs baseline: 1.9768x; 1.9768x over previous
//
#include <hip/hip_runtime.h>

// TemporalCausalMaps on MI355X (gfx950), round 8.
// Base = round 3 (best verified: 1198 us): one sample per block, one wave per
// block, serial (idx,n) cell walk, no s_barrier, LDS broadcasts, weights for
// wide stages hoisted per-cell (n is an inner loop var => no LICM blowup).
// New vs r3: (a) GRU recurrence uses __shfl broadcast of h (no LDS round-trip,
// no per-t syncs); (b) dual-accumulator dot chains (halve fmaf dep latency);
// (c) compiler may unroll hoisted t-loops (cross-t ILP); (d) cm3 uses all 64
// lanes (8x8 partial dots + shfl_xor reduce); (e) launch_bounds(64,2) => 256
// VGPR budget (grid-limited to 2 waves/SIMD, so registers are free).

#define NT 64

__device__ __forceinline__ void wave_sync() {
  asm volatile("s_waitcnt lgkmcnt(0)" ::: "memory");
}

__device__ __forceinline__ float sigm(float x) { return 1.0f / (1.0f + __expf(-x)); }
__device__ __forceinline__ float tanh_fast(float x) {
  x = fminf(15.0f, fmaxf(-15.0f, x));
  float e = __expf(2.0f * x);
  return (e - 1.0f) / (e + 1.0f);
}
__device__ __forceinline__ float leaky(float x) { return x >= 0.0f ? x : 0.01f * x; }

// dual-accumulator dot over N4 float4 chunks (N4 even in all uses)
template <int N4>
__device__ __forceinline__ float dotv(const float* __restrict__ w, const float* h) {
  const float4* w4 = reinterpret_cast<const float4*>(w);
  const float4* h4 = reinterpret_cast<const float4*>(h);
  float a0 = 0.0f, a1 = 0.0f;
#pragma unroll
  for (int i = 0; i < N4; i += 2) {
    float4 a = w4[i], b = h4[i];
    a0 = fmaf(a.x, b.x, a0); a0 = fmaf(a.y, b.y, a0);
    a0 = fmaf(a.z, b.z, a0); a0 = fmaf(a.w, b.w, a0);
    float4 c = w4[i + 1], d = h4[i + 1];
    a1 = fmaf(c.x, d.x, a1); a1 = fmaf(c.y, d.y, a1);
    a1 = fmaf(c.z, d.z, a1); a1 = fmaf(c.w, d.w, a1);
  }
  return a0 + a1;
}

// LDS layout (floats), 16B-aligned offsets. Total 3248 floats = 12992 B.
//  s_x   [8][48]  @0       s_h  [8][24] @384    s_g   [8][24] @576
//  s_gi  [8][72]  @768     s_y  [8][24] @1344
//  s_d1  [8][68]  @1584    s_d2 [8][68] @2128   s_dec [8][8]  @2672
//  s_ch  [8][2][32] @2736  (cond-net relu hidden, [t][src][k])
__global__ __launch_bounds__(NT, 2) void tcm_kernel(
    const float* __restrict__ z,
    const float* __restrict__ cond_w1, const float* __restrict__ cond_b1,
    const float* __restrict__ cond_w2, const float* __restrict__ cond_b2,
    const float* __restrict__ proj_w, const float* __restrict__ proj_b,
    const float* __restrict__ gpw, const float* __restrict__ gpb,
    const float* __restrict__ gru_wih, const float* __restrict__ gru_whh,
    const float* __restrict__ gru_bih, const float* __restrict__ gru_bhh,
    const float* __restrict__ cm_w1, const float* __restrict__ cm_b1,
    const float* __restrict__ cm_w2, const float* __restrict__ cm_b2,
    const float* __restrict__ cm_w3, const float* __restrict__ cm_b3,
    const int* __restrict__ endw,
    float* __restrict__ out, int Btot) {
  __shared__ __align__(16) float lds[3248];
  float* s_x   = lds;
  float* s_h   = lds + 384;
  float* s_g   = lds + 576;
  float* s_gi  = lds + 768;
  float* s_y   = lds + 1344;
  float* s_d1  = lds + 1584;   // stride 68
  float* s_d2  = lds + 2128;   // stride 68
  float* s_dec = lds + 2672;
  float* s_ch  = lds + 2736;

  const int lane = threadIdx.x;
  const int b = blockIdx.x;
  const int T = endw[0];

  s_dec[lane] = 0.0f;
  __syncthreads();

#pragma unroll 1
  for (int idx = 0; idx < T; ++idx) {
    const int L = idx + 1;
#pragma unroll 1
    for (int n = 0; n < 8; ++n) {
      // ---- stage 1a: z prefix copy (float4)
      {
        const float4* z4 = reinterpret_cast<const float4*>(
            z + ((size_t)n * Btot + b) * 256);
        float4* x4 = reinterpret_cast<float4*>(s_x);
#pragma unroll 1
        for (int it = lane; it < L * 8; it += NT) {
          int t = it >> 3, q = it & 7;
          x4[t * 12 + q] = z4[t * 8 + q];
        }
      }
      // ---- cond ph1: relu hidden, lane=(src,k)
      if (idx > 0) {
        int src = lane >> 5, k = lane & 31;
        int nn = (src == 0) ? n : (n > 0 ? n - 1 : 0);
        float w1v = cond_w1[nn * 32 + k];
        float b1v = cond_b1[nn * 32 + k];
#pragma unroll 2
        for (int t = 0; t < L; ++t) {
          float xv = s_dec[nn * 8 + t];
          s_ch[t * 64 + lane] = fmaxf(fmaf(xv, w1v, b1v), 0.0f);
        }
      }
      wave_sync();
      // ---- cond ph2: item-mapped (it = t*16 + c)
#pragma unroll 1
      for (int it = lane; it < L * 16; it += NT) {
        int t = it >> 4, c = it & 15;
        float v = 0.0f;
        if (c < 8) {
          if (t < idx)
            v = cond_b2[n * 8 + c] +
                dotv<8>(cond_w2 + (size_t)(n * 8 + c) * 32, s_ch + t * 64);
        } else {
          if (n > 0 && idx > 0)
            v = cond_b2[(n - 1) * 8 + (c - 8)] +
                dotv<8>(cond_w2 + (size_t)((n - 1) * 8 + c - 8) * 32,
                        s_ch + t * 64 + 32);
        }
        s_x[t * 48 + 32 + c] = v;
      }
      wave_sync();
      // ---- proj -> leaky: item-mapped (L*24 items across 64 lanes)
#pragma unroll 1
      for (int it = lane; it < L * 24; it += NT) {
        int t = it / 24, j = it % 24;
        float acc = proj_b[n * 24 + j] +
                    dotv<12>(proj_w + (size_t)(n * 24 + j) * 48, s_x + t * 48);
        s_h[t * 24 + j] = leaky(acc);
      }
      wave_sync();
      // ---- gru_proj: item-mapped
#pragma unroll 1
      for (int it = lane; it < L * 24; it += NT) {
        int t = it / 24, j = it % 24;
        s_g[t * 24 + j] = gpb[j] + dotv<6>(gpw + j * 24, s_h + t * 24);
      }
      wave_sync();
      // ---- GRU, 2 layers
      const float* srcp = s_g;
#pragma unroll 1
      for (int l = 0; l < 2; ++l) {
        const int nl = n * 2 + l;
        const float* wih = gru_wih + (size_t)nl * 72 * 24;
        const float* bih = gru_bih + nl * 72;
        // input gates: lane = row (0..63), rows 64..71 on lanes 0..7
        {
          float4 WA[6], WB[6];
          const float4* wa = reinterpret_cast<const float4*>(wih + (size_t)lane * 24);
          const float4* wb = reinterpret_cast<const float4*>(
              wih + (size_t)(64 + (lane & 7)) * 24);
#pragma unroll
          for (int i = 0; i < 6; ++i) { WA[i] = wa[i]; WB[i] = wb[i]; }
          float bA = bih[lane];
          float bB = bih[64 + (lane & 7)];
#pragma unroll 2
          for (int t = 0; t < L; ++t) {
            const float4* h4 = reinterpret_cast<const float4*>(srcp + t * 24);
            float a0 = bA, a1 = 0.0f, bacc = bB;
#pragma unroll
            for (int i = 0; i < 6; i += 2) {
              float4 h0 = h4[i], h1 = h4[i + 1];
              a0 = fmaf(WA[i].x, h0.x, a0); a0 = fmaf(WA[i].y, h0.y, a0);
              a0 = fmaf(WA[i].z, h0.z, a0); a0 = fmaf(WA[i].w, h0.w, a0);
              a1 = fmaf(WA[i + 1].x, h1.x, a1); a1 = fmaf(WA[i + 1].y, h1.y, a1);
              a1 = fmaf(WA[i + 1].z, h1.z, a1); a1 = fmaf(WA[i + 1].w, h1.w, a1);
              bacc = fmaf(WB[i].x, h0.x, bacc); bacc = fmaf(WB[i].y, h0.y, bacc);
              bacc = fmaf(WB[i].z, h0.z, bacc); bacc = fmaf(WB[i].w, h0.w, bacc);
              bacc = fmaf(WB[i + 1].x, h1.x, bacc); bacc = fmaf(WB[i + 1].y, h1.y, bacc);
              bacc = fmaf(WB[i + 1].z, h1.z, bacc); bacc = fmaf(WB[i + 1].w, h1.w, bacc);
            }
            s_gi[t * 72 + lane] = a0 + a1;
            if (lane < 8) s_gi[t * 72 + 64 + lane] = bacc;
          }
        }
        wave_sync();
        // recurrence: h broadcast via __shfl (lanes 0..23 hold h[j])
        {
          const float* whh = gru_whh + (size_t)nl * 72 * 24;
          const float* bhh = gru_bhh + nl * 72;
          int jm = lane < 24 ? lane : (lane < 48 ? lane - 24 : lane - 48);
          float4 Wr[6], Wz[6], Wn[6];
          {
            const float4* wr4 = reinterpret_cast<const float4*>(whh + jm * 24);
            const float4* wz4 = reinterpret_cast<const float4*>(whh + (24 + jm) * 24);
            const float4* wn4 = reinterpret_cast<const float4*>(whh + (48 + jm) * 24);
#pragma unroll
            for (int i = 0; i < 6; ++i) { Wr[i] = wr4[i]; Wz[i] = wz4[i]; Wn[i] = wn4[i]; }
          }
          float bR = bhh[jm], bZ = bhh[24 + jm], bN = bhh[48 + jm];
          float h = 0.0f;
#pragma unroll 1
          for (int t = 0; t < L; ++t) {
            float gr = bR, gz = bZ, gn = bN;
#pragma unroll
            for (int q = 0; q < 6; ++q) {
              float h0 = __shfl(h, q * 4 + 0);
              float h1 = __shfl(h, q * 4 + 1);
              float h2 = __shfl(h, q * 4 + 2);
              float h3 = __shfl(h, q * 4 + 3);
              gr = fmaf(Wr[q].x, h0, gr); gr = fmaf(Wr[q].y, h1, gr);
              gr = fmaf(Wr[q].z, h2, gr); gr = fmaf(Wr[q].w, h3, gr);
              gz = fmaf(Wz[q].x, h0, gz); gz = fmaf(Wz[q].y, h1, gz);
              gz = fmaf(Wz[q].z, h2, gz); gz = fmaf(Wz[q].w, h3, gz);
              gn = fmaf(Wn[q].x, h0, gn); gn = fmaf(Wn[q].y, h1, gn);
              gn = fmaf(Wn[q].z, h2, gn); gn = fmaf(Wn[q].w, h3, gn);
            }
            const float* gi = s_gi + t * 72;
            float r   = sigm(gi[jm] + gr);
            float zg  = sigm(gi[24 + jm] + gz);
            float nn2 = tanh_fast(gi[48 + jm] + r * gn);
            h = fmaf(zg, h - nn2, nn2);  // (1-z)*n + z*h
            if (lane < 24) s_y[t * 24 + lane] = h;
          }
        }
        wave_sync();
        srcp = s_y;
      }
      // ---- causal map layer 1: lane = j, reg weights, dual accum
      {
        float4 W[6];
        const float4* w4 = reinterpret_cast<const float4*>(
            cm_w1 + (size_t)(n * 64 + lane) * 24);
#pragma unroll
        for (int i = 0; i < 6; ++i) W[i] = w4[i];
        float bb = cm_b1[n * 64 + lane];
#pragma unroll 2
        for (int t = 0; t < L; ++t) {
          const float4* y4 = reinterpret_cast<const float4*>(s_y + t * 24);
          float a0 = bb, a1 = 0.0f;
#pragma unroll
          for (int i = 0; i < 6; i += 2) {
            float4 h0 = y4[i], h1 = y4[i + 1];
            a0 = fmaf(W[i].x, h0.x, a0); a0 = fmaf(W[i].y, h0.y, a0);
            a0 = fmaf(W[i].z, h0.z, a0); a0 = fmaf(W[i].w, h0.w, a0);
            a1 = fmaf(W[i + 1].x, h1.x, a1); a1 = fmaf(W[i + 1].y, h1.y, a1);
            a1 = fmaf(W[i + 1].z, h1.z, a1); a1 = fmaf(W[i + 1].w, h1.w, a1);
          }
          s_d1[t * 68 + lane] = fmaxf(a0 + a1, 0.0f);
        }
      }
      wave_sync();
      // ---- causal map layer 2: lane = j, reg weights, dual accum
      {
        float4 W[16];
        const float4* w4 = reinterpret_cast<const float4*>(
            cm_w2 + (size_t)(n * 64 + lane) * 64);
#pragma unroll
        for (int i = 0; i < 16; ++i) W[i] = w4[i];
        float bb = cm_b2[n * 64 + lane];
#pragma unroll 2
        for (int t = 0; t < L; ++t) {
          const float4* d4 = reinterpret_cast<const float4*>(s_d1 + t * 68);
          float a0 = bb, a1 = 0.0f;
#pragma unroll
          for (int i = 0; i < 16; i += 2) {
            float4 h0 = d4[i], h1 = d4[i + 1];
            a0 = fmaf(W[i].x, h0.x, a0); a0 = fmaf(W[i].y, h0.y, a0);
            a0 = fmaf(W[i].z, h0.z, a0); a0 = fmaf(W[i].w, h0.w, a0);
            a1 = fmaf(W[i + 1].x, h1.x, a1); a1 = fmaf(W[i + 1].y, h1.y, a1);
            a1 = fmaf(W[i + 1].z, h1.z, a1); a1 = fmaf(W[i + 1].w, h1.w, a1);
          }
          s_d2[t * 68 + lane] = fmaxf(a0 + a1, 0.0f);
        }
      }
      wave_sync();
      // ---- causal map layer 3: lane = (t, k) 8x8 partial dots + reduce
      {
        int t8 = lane >> 3, k8 = lane & 7;
        float part = 0.0f;
        if (t8 < L) {
          const float4* w4 = reinterpret_cast<const float4*>(cm_w3 + n * 64 + k8 * 8);
          const float4* d4 = reinterpret_cast<const float4*>(s_d2 + t8 * 68 + k8 * 8);
          float4 a = w4[0], hh = d4[0];
          part = fmaf(a.x, hh.x, part); part = fmaf(a.y, hh.y, part);
          part = fmaf(a.z, hh.z, part); part = fmaf(a.w, hh.w, part);
          float4 c = w4[1], dd = d4[1];
          part = fmaf(c.x, dd.x, part); part = fmaf(c.y, dd.y, part);
          part = fmaf(c.z, dd.z, part); part = fmaf(c.w, dd.w, part);
        }
        part += __shfl_xor(part, 1);
        part += __shfl_xor(part, 2);
        part += __shfl_xor(part, 4);
        if (t8 < L && k8 == 0) {
          float dv = cm_b3[n] + part;
          s_dec[n * 8 + t8] = dv;
          if (t8 == idx)
            out[((size_t)b * T + idx) * 8 + n] = dv;
        }
      }
      wave_sync();
    }
  }
}

extern "C" void kernel_launch(void* const* d_in, const int* in_sizes, int n_in,
                              void* d_out, int out_size, void* d_ws, size_t ws_size,
                              hipStream_t stream) {
  const float* z       = (const float*)d_in[0];
  const float* cond_w1 = (const float*)d_in[1];
  const float* cond_b1 = (const float*)d_in[2];
  const float* cond_w2 = (const float*)d_in[3];
  const float* cond_b2 = (const float*)d_in[4];
  const float* proj_w  = (const float*)d_in[5];
  const float* proj_b  = (const float*)d_in[6];
  const float* gpw     = (const float*)d_in[7];
  const float* gpb     = (const float*)d_in[8];
  const float* gru_wih = (const float*)d_in[9];
  const float* gru_whh = (const float*)d_in[10];
  const float* gru_bih = (const float*)d_in[11];
  const float* gru_bhh = (const float*)d_in[12];
  const float* cm_w1   = (const float*)d_in[13];
  const float* cm_b1   = (const float*)d_in[14];
  const float* cm_w2   = (const float*)d_in[15];
  const float* cm_b2   = (const float*)d_in[16];
  const float* cm_w3   = (const float*)d_in[17];
  const float* cm_b3   = (const float*)d_in[18];
  const int*   endw    = (const int*)d_in[19];
  float* out = (float*)d_out;

  int Btot = in_sizes[0] / (8 * 8 * 32);  // z: [8, B, 8, 32]

  tcm_kernel<<<Btot, NT, 0, stream>>>(
      z, cond_w1, cond_b1, cond_w2, cond_b2, proj_w, proj_b, gpw, gpb,
      gru_wih, gru_whh, gru_bih, gru_bhh, cm_w1, cm_b1, cm_w2, cm_b2,
      cm_w3, cm_b3, endw, out, Btot);
}